// Round 1
// baseline (271.710 us; speedup 1.0000x reference)
//
#include <hip/hip_runtime.h>
#include <hip/hip_bf16.h>

// ClauseExtractor: B=8,S=512,D=256,MAX_SPAN=100,NUM_TYPES=15, N spans=46250.
// Factorization: h_pre[b,(s,e)] = P[b,s] + Q[b,e],  P=E@Wenc[:256]+b_enc, Q=E@Wenc[256:]
// k2: per 64-span tile: h=relu(P+Q)+width -> bf16 LDS -> GEMM1^T (Wsc^T@h^T) -> sc
//     -> GEMM2^T (G^T@sc^T) -> scores+logits.

#define B_ 8
#define S_ 512
#define D_ 256
#define NSPANS 46250
#define NTILES 723  // ceil(46250/64)

typedef __bf16 bf16x8 __attribute__((ext_vector_type(8)));
typedef __bf16 bf16x4 __attribute__((ext_vector_type(4)));
typedef float float4_ __attribute__((ext_vector_type(4)));

#define MFMA16(a, b, c) __builtin_amdgcn_mfma_f32_16x16x32_bf16((a), (b), (c), 0, 0, 0)

// ---- workspace layout (bytes) ----
#define WS_STARTS 0u
#define WS_ENDS 185344u
#define WS_WENCP 370688u   // bf16[32][512][8]  = 262144 B
#define WS_WT 632832u      // bf16[32][256][8]  = 131072 B   (Wsc^T pack)
#define WS_GT 763904u      // bf16[32][16][8]   = 8192 B     (G^T pack)
#define WS_BSC 772096u     // f32[256]
#define WS_GB 773120u      // f32[16]
#define WS_PQ 786432u      // f32[4096][512] = 8388608 B
#define WS_NEED (WS_PQ + 8388608u)

__device__ __forceinline__ unsigned hswz(int row, unsigned byteInRow) {
  // XOR-swizzle: spreads 16-row column slices across 8 distinct 16B slots (G4)
  return (unsigned)row * 512u + (byteInRow ^ (((unsigned)row & 7u) << 4));
}

// ---------- kernel 0a: span meta ----------
__global__ void k0_meta(int* __restrict__ starts, int* __restrict__ ends) {
  int i = blockIdx.x;       // 0..511 start index
  int j = threadIdx.x;      // 0..127
  int len = min(100, S_ - i);
  if (j < len) {
    int cum;
    if (i <= 413) cum = 100 * i;
    else { int a = i - 413; cum = 41300 + 99 * a - (a * (a - 1)) / 2; }
    starts[cum + j] = i;
    ends[cum + j] = i + j;
  }
}

// ---------- kernel 0b: weight repack to bf16 fragment order ----------
__global__ void k0_pack(const float* __restrict__ Wenc, const float* __restrict__ Ws1,
                        const float* __restrict__ Wc1, const float* __restrict__ Ws2,
                        const float* __restrict__ Wc2, const float* __restrict__ bs1,
                        const float* __restrict__ bc1, const float* __restrict__ bs2,
                        const float* __restrict__ bc2, __bf16* __restrict__ WencP,
                        __bf16* __restrict__ WT, __bf16* __restrict__ GT,
                        float* __restrict__ bsc, float* __restrict__ gbv) {
  int idx = blockIdx.x * 256 + threadIdx.x;
  if (idx < 131072) {  // WencP[kc][n(512)][j]: n<256 -> Wenc[k][n] (P), else Wenc[256+k][n-256] (Q)
    int j = idx & 7, n = (idx >> 3) & 511, kc = idx >> 12;
    int k = kc * 8 + j;
    float v = (n < 256) ? Wenc[k * 256 + n] : Wenc[(256 + k) * 256 + (n - 256)];
    WencP[idx] = (__bf16)v;
  }
  int i2 = idx - 131072;  // WT[kc][c(256)][j] = Wsc[k][c] ; c<128 -> Ws1, else Wc1
  if (i2 >= 0 && i2 < 65536) {
    int j = i2 & 7, c = (i2 >> 3) & 255, kc = i2 >> 11;
    int k = kc * 8 + j;
    float v = (c < 128) ? Ws1[k * 128 + c] : Wc1[k * 128 + (c - 128)];
    WT[i2] = (__bf16)v;
  }
  int i3 = idx - (131072 + 65536);  // GT[kc][c(16)][j]: c0=Ws2 (k<128), c1..15=Wc2 (k>=128)
  if (i3 >= 0 && i3 < 4096) {
    int j = i3 & 7, c = (i3 >> 3) & 15, kc = i3 >> 7;
    int k = kc * 8 + j;
    float v = 0.f;
    if (c == 0) { if (k < 128) v = Ws2[k]; }
    else { if (k >= 128) v = Wc2[(k - 128) * 15 + (c - 1)]; }
    GT[i3] = (__bf16)v;
  }
  int i4 = idx - (131072 + 65536 + 4096);
  if (i4 >= 0 && i4 < 256) bsc[i4] = (i4 < 128) ? bs1[i4] : bc1[i4 - 128];
  if (i4 >= 256 && i4 < 272) { int c = i4 - 256; gbv[c] = (c == 0) ? bs2[0] : bc2[c - 1]; }
}

// ---------- kernel 1: PQ = E @ [Wenc_P | Wenc_Q]  (M=4096,N=512,K=256) ----------
__global__ __launch_bounds__(256) void k1_pq(const float* __restrict__ E,
                                             const __bf16* __restrict__ WencP,
                                             const float* __restrict__ benc,
                                             float* __restrict__ PQ) {
  const int tid = threadIdx.x;
  const int w = tid >> 6, lane = tid & 63, llo = lane & 15, lhi = lane >> 4;
  const int mbase = blockIdx.x * 64 + w * 16;
  const int nbase = blockIdx.y * 64;
  const float* aptr = E + (size_t)(mbase + llo) * 256 + lhi * 8;
  float4_ acc[4];
#pragma unroll
  for (int tn = 0; tn < 4; tn++) acc[tn] = (float4_){0.f, 0.f, 0.f, 0.f};
#pragma unroll
  for (int ks = 0; ks < 8; ++ks) {
    float4_ e0 = *(const float4_*)(aptr + ks * 32);
    float4_ e1 = *(const float4_*)(aptr + ks * 32 + 4);
    bf16x8 af;
#pragma unroll
    for (int j = 0; j < 4; j++) { af[j] = (__bf16)e0[j]; af[4 + j] = (__bf16)e1[j]; }
#pragma unroll
    for (int tn = 0; tn < 4; tn++) {
      bf16x8 bfr = *(const bf16x8*)(WencP + ((ks * 4 + lhi) * 512 + nbase + tn * 16 + llo) * 8);
      acc[tn] = MFMA16(af, bfr, acc[tn]);
    }
  }
#pragma unroll
  for (int tn = 0; tn < 4; tn++) {
    int col = nbase + tn * 16 + llo;
    float bb = (col < 256) ? benc[col] : 0.f;  // fold b_enc into P half
#pragma unroll
    for (int r = 0; r < 4; r++) {
      int row = mbase + lhi * 4 + r;
      PQ[(size_t)row * 512 + col] = acc[tn][r] + bb;
    }
  }
}

// ---------- kernel 2: fused span head ----------
__global__ __launch_bounds__(256) void k2_main(
    const float* __restrict__ PQ, const int* __restrict__ starts, const int* __restrict__ ends,
    const float* __restrict__ wtab, const __bf16* __restrict__ WT, const __bf16* __restrict__ GT,
    const float* __restrict__ bsc, const float* __restrict__ gbv,
    float* __restrict__ outS, float* __restrict__ outL) {
  __shared__ __align__(16) unsigned char h_lds[32768];  // [64][256] bf16, swizzled; reused for sc
  const int tile = blockIdx.x, b = blockIdx.y;
  const int tid = threadIdx.x;

  // ---- stage 1: build h = relu(P[s]+Q[e]) + width[e-s], cvt bf16 -> LDS ----
  {
    const int row = tid >> 2;        // 0..63 span row
    const int cq = tid & 3;          // column quarter (64 cols)
    const int span = tile * 64 + row;
    if (span < NSPANS) {
      const int s = starts[span];
      const int e = ends[span];
      const float* prow = PQ + (size_t)(b * S_ + s) * 512;
      const float* qrow = PQ + (size_t)(b * S_ + e) * 512 + 256;
      const float* wrow = wtab + (size_t)(e - s) * D_;
#pragma unroll
      for (int c0 = 0; c0 < 64; c0 += 8) {
        int c = cq * 64 + c0;
        float4_ p0 = *(const float4_*)(prow + c);
        float4_ p1 = *(const float4_*)(prow + c + 4);
        float4_ q0 = *(const float4_*)(qrow + c);
        float4_ q1 = *(const float4_*)(qrow + c + 4);
        float4_ w0 = *(const float4_*)(wrow + c);
        float4_ w1 = *(const float4_*)(wrow + c + 4);
        bf16x8 hv;
#pragma unroll
        for (int j = 0; j < 4; j++) {
          hv[j] = (__bf16)(fmaxf(p0[j] + q0[j], 0.f) + w0[j]);
          hv[4 + j] = (__bf16)(fmaxf(p1[j] + q1[j], 0.f) + w1[j]);
        }
        *(bf16x8*)(h_lds + hswz(row, (unsigned)(c * 2))) = hv;
      }
    } else {
      bf16x8 z = {};
#pragma unroll
      for (int c0 = 0; c0 < 64; c0 += 8)
        *(bf16x8*)(h_lds + hswz(row, (unsigned)((cq * 64 + c0) * 2))) = z;
    }
  }
  __syncthreads();

  const int w = tid >> 6, lane = tid & 63, llo = lane & 15, lhi = lane >> 4;

  // ---- stage 2: GEMM1^T: D1^T[scCol][span] = sum_k Wsc[k][scCol] * h[span][k]
  // wave w owns sc-cols [64w, 64w+64); acc[tm][tn]: tm sc-col tile, tn span tile
  float4_ acc[4][4];
#pragma unroll
  for (int tm = 0; tm < 4; tm++)
#pragma unroll
    for (int tn = 0; tn < 4; tn++) acc[tm][tn] = (float4_){0.f, 0.f, 0.f, 0.f};

#pragma unroll
  for (int ks = 0; ks < 8; ++ks) {
    bf16x8 af[4], bfr[4];
#pragma unroll
    for (int tm = 0; tm < 4; tm++)
      af[tm] = *(const bf16x8*)(WT + ((ks * 4 + lhi) * 256 + w * 64 + tm * 16 + llo) * 8);
#pragma unroll
    for (int tn = 0; tn < 4; tn++)
      bfr[tn] = *(const bf16x8*)(h_lds + hswz(tn * 16 + llo, (unsigned)(ks * 64 + lhi * 16)));
#pragma unroll
    for (int tm = 0; tm < 4; tm++)
#pragma unroll
      for (int tn = 0; tn < 4; tn++) acc[tm][tn] = MFMA16(af[tm], bfr[tn], acc[tm][tn]);
  }
  __syncthreads();  // all h reads done before overwriting LDS with sc

  // epilogue: sc = relu(acc + bsc), write row-major [64][256] bf16 (b64 stores: 4 consecutive cols)
#pragma unroll
  for (int tm = 0; tm < 4; tm++) {
    float4_ bq = *(const float4_*)(bsc + w * 64 + tm * 16 + lhi * 4);
#pragma unroll
    for (int tn = 0; tn < 4; tn++) {
      bf16x4 x;
#pragma unroll
      for (int r = 0; r < 4; r++) x[r] = (__bf16)fmaxf(acc[tm][tn][r] + bq[r], 0.f);
      *(bf16x4*)(h_lds + hswz(tn * 16 + llo, (unsigned)((w * 64 + tm * 16 + lhi * 4) * 2))) = x;
    }
  }
  __syncthreads();

  // ---- stage 3: GEMM2^T: D2^T[gcol][span] = sum_k G[k][gcol] * sc[span][k]
  // wave w owns span rows [16w, 16w+16)
  float4_ a2 = (float4_){0.f, 0.f, 0.f, 0.f};
#pragma unroll
  for (int ks = 0; ks < 8; ++ks) {
    bf16x8 ga = *(const bf16x8*)(GT + ((ks * 4 + lhi) * 16 + llo) * 8);
    bf16x8 sb = *(const bf16x8*)(h_lds + hswz(w * 16 + llo, (unsigned)(ks * 64 + lhi * 16)));
    a2 = MFMA16(ga, sb, a2);
  }
  const int span2 = tile * 64 + w * 16 + llo;
  if (span2 < NSPANS) {
    float4_ gq = *(const float4_*)(gbv + lhi * 4);
    size_t base = (size_t)b * NSPANS + span2;
#pragma unroll
    for (int r = 0; r < 4; r++) {
      float v = a2[r] + gq[r];
      int gcol = lhi * 4 + r;
      if (gcol == 0) outS[base] = v;                    // span_scores (B,N)
      else outL[base * 15 + (gcol - 1)] = v;            // type_logits (B,N,15)
    }
  }
}

extern "C" void kernel_launch(void* const* d_in, const int* in_sizes, int n_in,
                              void* d_out, int out_size, void* d_ws, size_t ws_size,
                              hipStream_t stream) {
  if (ws_size < (size_t)WS_NEED) return;  // need ~9.2 MB scratch
  const float* E = (const float*)d_in[0];
  const float* Wenc = (const float*)d_in[1];
  const float* benc = (const float*)d_in[2];
  const float* wtab = (const float*)d_in[3];
  const float* Ws1 = (const float*)d_in[4];
  const float* bs1 = (const float*)d_in[5];
  const float* Ws2 = (const float*)d_in[6];
  const float* bs2 = (const float*)d_in[7];
  const float* Wc1 = (const float*)d_in[8];
  const float* bc1 = (const float*)d_in[9];
  const float* Wc2 = (const float*)d_in[10];
  const float* bc2 = (const float*)d_in[11];

  unsigned char* ws = (unsigned char*)d_ws;
  int* starts = (int*)(ws + WS_STARTS);
  int* ends = (int*)(ws + WS_ENDS);
  __bf16* WencP = (__bf16*)(ws + WS_WENCP);
  __bf16* WT = (__bf16*)(ws + WS_WT);
  __bf16* GT = (__bf16*)(ws + WS_GT);
  float* bsc = (float*)(ws + WS_BSC);
  float* gbv = (float*)(ws + WS_GB);
  float* PQ = (float*)(ws + WS_PQ);

  float* outS = (float*)d_out;                       // 8*46250
  float* outL = outS + (size_t)B_ * NSPANS;          // 8*46250*15

  k0_meta<<<dim3(512), dim3(128), 0, stream>>>(starts, ends);
  k0_pack<<<dim3(786), dim3(256), 0, stream>>>(Wenc, Ws1, Wc1, Ws2, Wc2, bs1, bc1, bs2, bc2,
                                               WencP, WT, GT, bsc, gbv);
  k1_pq<<<dim3(64, 8), dim3(256), 0, stream>>>(E, WencP, benc, PQ);
  k2_main<<<dim3(NTILES, B_), dim3(256), 0, stream>>>(PQ, starts, ends, wtab, WT, GT, bsc, gbv,
                                                      outS, outL);
}